// Round 2
// baseline (101.488 us; speedup 1.0000x reference)
//
#include <hip/hip_runtime.h>
#include <hip/hip_bf16.h>
#include <stdint.h>

typedef __attribute__((ext_vector_type(8))) __bf16 bf16x8;
typedef __attribute__((ext_vector_type(16))) float floatx16;

#if __has_builtin(__builtin_amdgcn_exp2f)
#define EXP2F(x) __builtin_amdgcn_exp2f(x)
#else
#define EXP2F(x) exp2f(x)
#endif

#define GAS __attribute__((address_space(1)))
#define LAS __attribute__((address_space(3)))

// sqrt(2*log2(e)): baked into normalized rows so dot = 2*log2(e)*cos and
// sim = exp2(dot) = exp(cos/0.5) with zero epilogue multiplies.
#define SCALE_SQRT 1.69864359f

// ---------------- prep: int64-probe labels + normalize -----------------------
__global__ __launch_bounds__(256) void k_prep(const float* __restrict__ x,
                                              const int* __restrict__ raw,
                                              ushort* __restrict__ xb,
                                              int* __restrict__ lab, int N) {
  const int row = (blockIdx.x * 256 + threadIdx.x) >> 6;  // one wave per row
  const int lane = threadIdx.x & 63;
  if (row >= N) return;
  // parallel int64 detection: odd words all zero => labels are int64
  const int probe = raw[2 * lane + 1];
  const bool is64 = (__ballot(probe != 0) == 0ull);
  const float2 v = ((const float2*)(x + (size_t)row * 128))[lane];
  float ss = v.x * v.x + v.y * v.y;
#pragma unroll
  for (int m = 1; m < 64; m <<= 1) ss += __shfl_xor(ss, m, 64);
  const float rn = SCALE_SQRT / fmaxf(sqrtf(ss), 1e-12f);
  __hip_bfloat162 o;
  o.x = __float2bfloat16(v.x * rn);
  o.y = __float2bfloat16(v.y * rn);
  ((__hip_bfloat162*)xb)[row * 64 + lane] = o;
  if (lane == 0) lab[row] = is64 ? raw[2 * row] : raw[row];
}

// ---------------- main: SYMMETRIC upper-triangle exp(x x^T/T) sums -----------
// sim is symmetric => row sums == col sums. Enumerate 128x128 blocks (s,u)
// with u >= s only (2080 blocks vs 4096): off-diagonal blocks contribute row
// sums to strip s AND column sums to strip u; diagonal blocks (own transpose)
// contribute row sums only. Halves MFMA/exp2/LDS/staging work.
// Partials: plane p in [0,nstrip), row r — written by exactly ONE block
// (row-part: block (strip(r), p) for p>=strip(r); col-part: block (p, strip(r))
// for p<strip(r)) => dense, deterministic, atomic-free.
// Block: 256 thr = 4 waves; wave owns 32 rows x all 64 cols of each j-tile.
// A fragments from global (xb = 2 MB, L2-resident); B block staged once in
// LDS (32 KB, XOR-16 source-permuted swizzle), consumed by both j-tiles.
__global__ __launch_bounds__(256, 2) void k_sim(const ushort* __restrict__ xb,
                                                const int* __restrict__ lab,
                                                float* __restrict__ pneg,
                                                float* __restrict__ ppos,
                                                int N) {
  __shared__ ushort ldsB[128 * 128];  // 32 KB; reused as col-flush scratch
  const int tid = threadIdx.x;
  const int lane = tid & 63;
  const int wv = tid >> 6;
  const int l31 = lane & 31, g2 = lane >> 5;
  const int l15 = lane & 15, g4 = lane >> 4;

  // decode blockIdx -> (s,u) pair, u >= s, bid = u*(u+1)/2 + s
  const int bid = blockIdx.x;
  int u = (int)((sqrtf(8.0f * (float)bid + 1.0f) - 1.0f) * 0.5f);
  while ((u + 1) * (u + 2) / 2 <= bid) ++u;
  while (u * (u + 1) / 2 > bid) --u;
  const int s = bid - u * (u + 1) / 2;
  const int i0 = s * 128;   // A rows (strip)
  const int jb0 = u * 128;  // B rows (block)

  // ---- stage B block (128 rows, 32 KB) once ----
#pragma unroll
  for (int it = 0; it < 8; ++it) {
    const int r0 = it * 16 + wv * 4;  // wave-uniform LDS row base
    const int lr = r0 + g4;
    const int kb = l15 ^ (lr & 15);
    const ushort* gp = xb + (size_t)(jb0 + lr) * 128 + kb * 8;
    __builtin_amdgcn_global_load_lds((GAS void*)gp, (LAS void*)&ldsB[r0 * 128], 16, 0, 0);
  }

  // ---- A fragments straight from global (L2-hot): rows wv*32+l31 ----
  const int arow = i0 + wv * 32 + l31;
  bf16x8 af[8];
#pragma unroll
  for (int kt = 0; kt < 8; ++kt)
    af[kt] = *(const bf16x8*)(xb + (size_t)arow * 128 + (kt * 2 + g2) * 8);

  // per-lane row labels + accumulators (C/D 32x32: col=lane&31,
  // row = (reg&3) + 8*(reg>>2) + 4*(lane>>5))
  int li[16];
  float neg[16], pos[16];
#pragma unroll
  for (int r = 0; r < 16; ++r) {
    li[r] = lab[i0 + wv * 32 + (r & 3) + 8 * (r >> 2) + 4 * g2];
    neg[r] = 0.0f;
    pos[r] = 0.0f;
  }
  const bool offd = (u != s);
  __syncthreads();  // B staged (vmcnt drained per wave at barrier)

  float cnT[2][2], cpT[2][2];  // per-tile, per-half column partials
#pragma unroll
  for (int tile = 0; tile < 2; ++tile) {
    const int j0 = jb0 + tile * 64;
    const int lj0 = lab[j0 + l31];       // column labels, both halves
    const int lj1 = lab[j0 + 32 + l31];

    floatx16 acc[2];
    acc[0] = (floatx16)(0.0f);
    acc[1] = (floatx16)(0.0f);
    __builtin_amdgcn_s_setprio(1);
#pragma unroll
    for (int kt = 0; kt < 8; ++kt) {
#pragma unroll
      for (int h = 0; h < 2; ++h) {
        const int brow = tile * 64 + h * 32 + l31;
        const int bkb = (kt * 2 + g2) ^ (brow & 15);
        const bf16x8 bfr = *(const bf16x8*)&ldsB[brow * 128 + bkb * 8];
        acc[h] = __builtin_amdgcn_mfma_f32_32x32x16_bf16(af[kt], bfr, acc[h], 0, 0, 0);
      }
    }
    __builtin_amdgcn_s_setprio(0);

    // ---- epilogue: exp2, diag-skip (diag blocks), row+col accumulation ----
    float cn0 = 0.0f, cn1 = 0.0f, cp0 = 0.0f, cp1 = 0.0f;
    if (offd) {
#pragma unroll
      for (int h = 0; h < 2; ++h) {
        const int lj = h ? lj1 : lj0;
#pragma unroll
        for (int r = 0; r < 16; ++r) {
          const float e = EXP2F(acc[h][r]);
          const bool mt = (li[r] == lj);
          neg[r] += e;
          pos[r] += mt ? e : 0.0f;
          if (h) { cn1 += e; cp1 += mt ? e : 0.0f; }
          else   { cn0 += e; cp0 += mt ? e : 0.0f; }
        }
      }
    } else {
      const int dlt = tile * 64;  // j0 - i0 for diagonal blocks
#pragma unroll
      for (int h = 0; h < 2; ++h) {
        const int lj = h ? lj1 : lj0;
        const int jc = h * 32 + l31 + dlt;
#pragma unroll
        for (int r = 0; r < 16; ++r) {
          float e = EXP2F(acc[h][r]);
          const int ir = wv * 32 + (r & 3) + 8 * (r >> 2) + 4 * g2;
          if (ir == jc) e = 0.0f;  // exclude self-similarity exactly
          neg[r] += e;
          pos[r] += (li[r] == lj) ? e : 0.0f;
        }
      }
    }
    cnT[tile][0] = cn0; cnT[tile][1] = cn1;
    cpT[tile][0] = cp0; cpT[tile][1] = cp1;
  }

  // ---- row flush: reduce over 32 col-lanes; single writer lane per row ----
  // plane u, rows of strip s
#pragma unroll
  for (int r = 0; r < 16; ++r) {
    float n = neg[r], p = pos[r];
#pragma unroll
    for (int m = 1; m < 32; m <<= 1) {
      n += __shfl_xor(n, m, 64);
      p += __shfl_xor(p, m, 64);
    }
    if (l31 == 0) {
      const int row = i0 + wv * 32 + (r & 3) + 8 * (r >> 2) + 4 * g2;
      pneg[(size_t)u * N + row] = n;
      ppos[(size_t)u * N + row] = p;
    }
  }

  // ---- col flush (off-diagonal only): plane s, rows of block u ----
  if (offd) {
    __syncthreads();  // all ldsB reads done; reuse as float scratch
    float* cb = (float*)ldsB;  // [wv][tile][h][np][32] = 4 KB
#pragma unroll
    for (int tile = 0; tile < 2; ++tile) {
#pragma unroll
      for (int h = 0; h < 2; ++h) {
        // lanes l and l+32 hold partials of the SAME column (different rows)
        float a = cnT[tile][h] + __shfl_xor(cnT[tile][h], 32, 64);
        float b = cpT[tile][h] + __shfl_xor(cpT[tile][h], 32, 64);
        if (lane < 32) {
          cb[(((wv * 2 + tile) * 2 + h) * 2 + 0) * 32 + l31] = a;
          cb[(((wv * 2 + tile) * 2 + h) * 2 + 1) * 32 + l31] = b;
        }
      }
    }
    __syncthreads();
    // 256 threads <-> 256 (tile,h,np,col) entries: sum 4 waves, store
    const int c5 = tid & 31;
    const int np = (tid >> 5) & 1;
    const int h = (tid >> 6) & 1;
    const int t = (tid >> 7) & 1;
    float v = 0.0f;
#pragma unroll
    for (int w = 0; w < 4; ++w)
      v += cb[(((w * 2 + t) * 2 + h) * 2 + np) * 32 + c5];
    const int jrow = jb0 + t * 64 + h * 32 + c5;
    if (np == 0) pneg[(size_t)s * N + jrow] = v;
    else         ppos[(size_t)s * N + jrow] = v;
  }
}

// ---------------- finalize: parallel over 32 blocks, 1 row/thread ------------
__global__ __launch_bounds__(256) void k_final(const float* __restrict__ pneg,
                                               const float* __restrict__ ppos,
                                               const int* __restrict__ lab,
                                               double* __restrict__ partial,
                                               int N, int nstrip) {
  __shared__ int h[64];
  __shared__ double wsum[4];
  const int tid = threadIdx.x;
  if (tid < 64) h[tid] = 0;
  __syncthreads();
  for (int i = tid; i < N; i += 256) atomicAdd(&h[lab[i] & 63], 1);
  __syncthreads();
  const int r = blockIdx.x * 256 + tid;
  double v = 0.0;
  if (r < N) {
    float n = 0.0f, p = 0.0f;
#pragma unroll 8
    for (int cc = 0; cc < nstrip; ++cc) {
      n += pneg[(size_t)cc * N + r];
      p += ppos[(size_t)cc * N + r];
    }
    const float cnt = (float)(h[lab[r] & 63] - 1);
    v = (double)logf(n * cnt / p);
  }
#pragma unroll
  for (int m = 1; m < 64; m <<= 1) v += __shfl_xor(v, m, 64);
  if ((tid & 63) == 0) wsum[tid >> 6] = v;
  __syncthreads();
  if (tid == 0) partial[blockIdx.x] = wsum[0] + wsum[1] + wsum[2] + wsum[3];
}

__global__ __launch_bounds__(64) void k_write(const double* __restrict__ partial,
                                              float* __restrict__ out, int nfb, int N) {
  const int l = threadIdx.x;
  double v = 0.0;
  for (int i = l; i < nfb; i += 64) v += partial[i];
#pragma unroll
  for (int m = 1; m < 64; m <<= 1) v += __shfl_xor(v, m, 64);
  if (l == 0) out[0] = (float)(v / (double)N);
}

extern "C" void kernel_launch(void* const* d_in, const int* in_sizes, int n_in,
                              void* d_out, int out_size, void* d_ws, size_t ws_size,
                              hipStream_t stream) {
  const float* x = (const float*)d_in[0];
  const int* raw_label = (const int*)d_in[1];
  const int N = in_sizes[1];  // 8192
  const int nstrip = N / 128; // 64
  char* ws = (char*)d_ws;
  ushort* xb = (ushort*)ws;                          // N*128 bf16 = 2 MB
  float* pneg = (float*)(ws + (size_t)N * 128 * 2);  // nstrip*N f32 = 2 MB
  float* ppos = pneg + (size_t)nstrip * N;           // nstrip*N f32 = 2 MB
  int* lab = (int*)(ppos + (size_t)nstrip * N);      // N ints = 32 KB
  double* partial = (double*)(lab + N);              // <=64 doubles
  float* out = (float*)d_out;

  const int pairs = nstrip * (nstrip + 1) / 2;  // 2080 upper-tri blocks
  const int nfb = (N + 255) / 256;              // 32 finalize blocks

  k_prep<<<dim3(N / 4), dim3(256), 0, stream>>>(x, raw_label, xb, lab, N);
  k_sim<<<dim3(pairs), dim3(256), 0, stream>>>(xb, lab, pneg, ppos, N);
  k_final<<<dim3(nfb), dim3(256), 0, stream>>>(pneg, ppos, lab, partial, N, nstrip);
  k_write<<<dim3(1), dim3(64), 0, stream>>>(partial, out, nfb, N);
}

// Round 3
// 99.646 us; speedup vs baseline: 1.0185x; 1.0185x over previous
//
#include <hip/hip_runtime.h>
#include <hip/hip_bf16.h>
#include <stdint.h>

typedef __attribute__((ext_vector_type(8))) __bf16 bf16x8;
typedef __attribute__((ext_vector_type(16))) float floatx16;

#if __has_builtin(__builtin_amdgcn_exp2f)
#define EXP2F(x) __builtin_amdgcn_exp2f(x)
#else
#define EXP2F(x) exp2f(x)
#endif

#define GAS __attribute__((address_space(1)))
#define LAS __attribute__((address_space(3)))

// sqrt(2*log2(e)): baked into normalized rows so dot = 2*log2(e)*cos and
// sim = exp2(dot) = exp(cos/0.5) with zero epilogue multiplies.
#define SCALE_SQRT 1.69864359f

// ---------------- prep: int64-probe labels + normalize -----------------------
__global__ __launch_bounds__(256) void k_prep(const float* __restrict__ x,
                                              const int* __restrict__ raw,
                                              ushort* __restrict__ xb,
                                              int* __restrict__ lab, int N) {
  const int row = (blockIdx.x * 256 + threadIdx.x) >> 6;  // one wave per row
  const int lane = threadIdx.x & 63;
  if (row >= N) return;
  // parallel int64 detection: odd words all zero => labels are int64
  const int probe = raw[2 * lane + 1];
  const bool is64 = (__ballot(probe != 0) == 0ull);
  const float2 v = ((const float2*)(x + (size_t)row * 128))[lane];
  float ss = v.x * v.x + v.y * v.y;
#pragma unroll
  for (int m = 1; m < 64; m <<= 1) ss += __shfl_xor(ss, m, 64);
  const float rn = SCALE_SQRT / fmaxf(sqrtf(ss), 1e-12f);
  __hip_bfloat162 o;
  o.x = __float2bfloat16(v.x * rn);
  o.y = __float2bfloat16(v.y * rn);
  ((__hip_bfloat162*)xb)[row * 64 + lane] = o;
  if (lane == 0) lab[row] = is64 ? raw[2 * row] : raw[row];
}

// ---------------- main: SYMMETRIC upper-triangle exp(x x^T/T) sums -----------
// One 128x128 block pair (s,u), u>=s, per workgroup (2080 blocks). Row sums of
// the pair go to plane u (rows of strip s); col sums go to plane s (rows of
// strip u). Unique writer per (plane,row) => atomic-free. R3 focus: latency
// hiding — minimal register state (byte-packed labels; col partials spilled to
// a dedicated LDS scratch per tile), no setprio, all label loads hoisted
// before the single staging barrier.
__global__ __launch_bounds__(256, 2) void k_sim(const ushort* __restrict__ xb,
                                                const int* __restrict__ lab,
                                                float* __restrict__ pneg,
                                                float* __restrict__ ppos,
                                                int N) {
  __shared__ ushort ldsB[128 * 128];       // 32 KB, XOR-16 swizzled B block
  __shared__ float cb[4 * 2 * 2 * 2 * 32]; // 4 KB col scratch [wv][t][h][np][col]
  const int tid = threadIdx.x;
  const int lane = tid & 63;
  const int wv = tid >> 6;
  const int l31 = lane & 31, g2 = lane >> 5;
  const int l15 = lane & 15, g4 = lane >> 4;

  // decode blockIdx -> (s,u) pair, u >= s, bid = u*(u+1)/2 + s
  const int bid = blockIdx.x;
  int u = (int)((sqrtf(8.0f * (float)bid + 1.0f) - 1.0f) * 0.5f);
  while ((u + 1) * (u + 2) / 2 <= bid) ++u;
  while (u * (u + 1) / 2 > bid) --u;
  const int s = bid - u * (u + 1) / 2;
  const int i0 = s * 128;   // A rows (strip)
  const int jb0 = u * 128;  // B rows (block)

  // ---- stage B block (128 rows, 32 KB) ----
#pragma unroll
  for (int it = 0; it < 8; ++it) {
    const int r0 = it * 16 + wv * 4;  // wave-uniform LDS row base
    const int lr = r0 + g4;
    const int kb = l15 ^ (lr & 15);
    const ushort* gp = xb + (size_t)(jb0 + lr) * 128 + kb * 8;
    __builtin_amdgcn_global_load_lds((GAS void*)gp, (LAS void*)&ldsB[r0 * 128], 16, 0, 0);
  }

  // ---- A fragments straight from global (L2-hot): rows wv*32+l31 ----
  const int arow = i0 + wv * 32 + l31;
  bf16x8 af[8];
#pragma unroll
  for (int kt = 0; kt < 8; ++kt)
    af[kt] = *(const bf16x8*)(xb + (size_t)arow * 128 + (kt * 2 + g2) * 8);

  // row labels byte-packed (C=64 < 256 so low byte is exact): word q holds
  // rows wv*32 + 8q + 4*g2 + {0..3}  (C/D row = (r&3) + 8*(r>>2) + 4*g2)
  int liw[4];
#pragma unroll
  for (int q = 0; q < 4; ++q) {
    const int rb = i0 + wv * 32 + 8 * q + 4 * g2;
    liw[q] = (lab[rb] & 255) | ((lab[rb + 1] & 255) << 8) |
             ((lab[rb + 2] & 255) << 16) | ((lab[rb + 3] & 255) << 24);
  }
  // column labels for both tiles/halves, hoisted before the barrier
  int lj[4];
#pragma unroll
  for (int t = 0; t < 2; ++t)
#pragma unroll
    for (int h = 0; h < 2; ++h) lj[t * 2 + h] = lab[jb0 + t * 64 + h * 32 + l31];

  floatx16 vneg = (floatx16)(0.0f), vpos = (floatx16)(0.0f);
  const bool offd = (u != s);
  __syncthreads();  // B staged (vmcnt drained per wave at barrier)

#pragma unroll
  for (int tile = 0; tile < 2; ++tile) {
    floatx16 acc0 = (floatx16)(0.0f), acc1 = (floatx16)(0.0f);
#pragma unroll
    for (int kt = 0; kt < 8; ++kt) {
      const int br0 = tile * 64 + l31;
      const int br1 = tile * 64 + 32 + l31;
      const bf16x8 b0 = *(const bf16x8*)&ldsB[br0 * 128 + (((kt * 2 + g2) ^ (br0 & 15)) * 8)];
      const bf16x8 b1 = *(const bf16x8*)&ldsB[br1 * 128 + (((kt * 2 + g2) ^ (br1 & 15)) * 8)];
      acc0 = __builtin_amdgcn_mfma_f32_32x32x16_bf16(af[kt], b0, acc0, 0, 0, 0);
      acc1 = __builtin_amdgcn_mfma_f32_32x32x16_bf16(af[kt], b1, acc1, 0, 0, 0);
    }

    // ---- epilogue ----
    if (offd) {
      float cn0 = 0.0f, cn1 = 0.0f, cp0 = 0.0f, cp1 = 0.0f;
#pragma unroll
      for (int r = 0; r < 16; ++r) {
        const int lr = (liw[r >> 2] >> ((r & 3) * 8)) & 255;
        const float e0 = EXP2F(acc0[r]);
        const float e1 = EXP2F(acc1[r]);
        const float s0 = (lr == lj[tile * 2 + 0]) ? e0 : 0.0f;
        const float s1 = (lr == lj[tile * 2 + 1]) ? e1 : 0.0f;
        vneg[r] += e0 + e1;
        vpos[r] += s0 + s1;
        cn0 += e0; cp0 += s0;
        cn1 += e1; cp1 += s1;
      }
      // col partials -> LDS scratch now (per-wave slot, no barrier needed yet)
      // lanes l and l+32 hold the same column (different rows): fold, store.
      {
        float a0 = cn0 + __shfl_xor(cn0, 32, 64);
        float b0 = cp0 + __shfl_xor(cp0, 32, 64);
        float a1 = cn1 + __shfl_xor(cn1, 32, 64);
        float b1 = cp1 + __shfl_xor(cp1, 32, 64);
        if (lane < 32) {
          cb[(((wv * 2 + tile) * 2 + 0) * 2 + 0) * 32 + l31] = a0;
          cb[(((wv * 2 + tile) * 2 + 0) * 2 + 1) * 32 + l31] = b0;
          cb[(((wv * 2 + tile) * 2 + 1) * 2 + 0) * 32 + l31] = a1;
          cb[(((wv * 2 + tile) * 2 + 1) * 2 + 1) * 32 + l31] = b1;
        }
      }
    } else {
      const int jc0 = tile * 64 + l31;       // global-diag col (h=0) rel strip
      const int jc1 = tile * 64 + 32 + l31;  // h=1
#pragma unroll
      for (int r = 0; r < 16; ++r) {
        const int lr = (liw[r >> 2] >> ((r & 3) * 8)) & 255;
        const int ir = wv * 32 + (r & 3) + 8 * (r >> 2) + 4 * g2;
        float e0 = EXP2F(acc0[r]);
        float e1 = EXP2F(acc1[r]);
        if (ir == jc0) e0 = 0.0f;  // exclude self-similarity exactly
        if (ir == jc1) e1 = 0.0f;
        vneg[r] += e0 + e1;
        vpos[r] += ((lr == lj[tile * 2 + 0]) ? e0 : 0.0f) +
                   ((lr == lj[tile * 2 + 1]) ? e1 : 0.0f);
      }
    }
  }

  // ---- row flush: reduce over 32 col-lanes; single writer lane per row ----
#pragma unroll
  for (int r = 0; r < 16; ++r) {
    float n = vneg[r], p = vpos[r];
#pragma unroll
    for (int m = 1; m < 32; m <<= 1) {
      n += __shfl_xor(n, m, 64);
      p += __shfl_xor(p, m, 64);
    }
    if (l31 == 0) {
      const int row = i0 + wv * 32 + (r & 3) + 8 * (r >> 2) + 4 * g2;
      pneg[(size_t)u * N + row] = n;
      ppos[(size_t)u * N + row] = p;
    }
  }

  // ---- col flush (off-diagonal only): plane s, rows of block u ----
  if (offd) {
    __syncthreads();  // all cb writes visible
    // 256 threads <-> 256 (tile,h,np,col) entries: sum 4 waves, store
    const int c5 = tid & 31;
    const int np = (tid >> 5) & 1;
    const int h = (tid >> 6) & 1;
    const int t = (tid >> 7) & 1;
    float v = 0.0f;
#pragma unroll
    for (int w = 0; w < 4; ++w)
      v += cb[(((w * 2 + t) * 2 + h) * 2 + np) * 32 + c5];
    const int jrow = jb0 + t * 64 + h * 32 + c5;
    if (np == 0) pneg[(size_t)s * N + jrow] = v;
    else         ppos[(size_t)s * N + jrow] = v;
  }
}

// ---------------- finalize: parallel over 32 blocks, 1 row/thread ------------
__global__ __launch_bounds__(256) void k_final(const float* __restrict__ pneg,
                                               const float* __restrict__ ppos,
                                               const int* __restrict__ lab,
                                               double* __restrict__ partial,
                                               int N, int nstrip) {
  __shared__ int h[64];
  __shared__ double wsum[4];
  const int tid = threadIdx.x;
  if (tid < 64) h[tid] = 0;
  __syncthreads();
  for (int i = tid; i < N; i += 256) atomicAdd(&h[lab[i] & 63], 1);
  __syncthreads();
  const int r = blockIdx.x * 256 + tid;
  double v = 0.0;
  if (r < N) {
    float n = 0.0f, p = 0.0f;
#pragma unroll 8
    for (int cc = 0; cc < nstrip; ++cc) {
      n += pneg[(size_t)cc * N + r];
      p += ppos[(size_t)cc * N + r];
    }
    const float cnt = (float)(h[lab[r] & 63] - 1);
    v = (double)logf(n * cnt / p);
  }
#pragma unroll
  for (int m = 1; m < 64; m <<= 1) v += __shfl_xor(v, m, 64);
  if ((tid & 63) == 0) wsum[tid >> 6] = v;
  __syncthreads();
  if (tid == 0) partial[blockIdx.x] = wsum[0] + wsum[1] + wsum[2] + wsum[3];
}

__global__ __launch_bounds__(64) void k_write(const double* __restrict__ partial,
                                              float* __restrict__ out, int nfb, int N) {
  const int l = threadIdx.x;
  double v = 0.0;
  for (int i = l; i < nfb; i += 64) v += partial[i];
#pragma unroll
  for (int m = 1; m < 64; m <<= 1) v += __shfl_xor(v, m, 64);
  if (l == 0) out[0] = (float)(v / (double)N);
}

extern "C" void kernel_launch(void* const* d_in, const int* in_sizes, int n_in,
                              void* d_out, int out_size, void* d_ws, size_t ws_size,
                              hipStream_t stream) {
  const float* x = (const float*)d_in[0];
  const int* raw_label = (const int*)d_in[1];
  const int N = in_sizes[1];  // 8192
  const int nstrip = N / 128; // 64
  char* ws = (char*)d_ws;
  ushort* xb = (ushort*)ws;                          // N*128 bf16 = 2 MB
  float* pneg = (float*)(ws + (size_t)N * 128 * 2);  // nstrip*N f32 = 2 MB
  float* ppos = pneg + (size_t)nstrip * N;           // nstrip*N f32 = 2 MB
  int* lab = (int*)(ppos + (size_t)nstrip * N);      // N ints = 32 KB
  double* partial = (double*)(lab + N);              // <=64 doubles
  float* out = (float*)d_out;

  const int pairs = nstrip * (nstrip + 1) / 2;  // 2080 upper-tri blocks
  const int nfb = (N + 255) / 256;              // 32 finalize blocks

  k_prep<<<dim3(N / 4), dim3(256), 0, stream>>>(x, raw_label, xb, lab, N);
  k_sim<<<dim3(pairs), dim3(256), 0, stream>>>(xb, lab, pneg, ppos, N);
  k_final<<<dim3(nfb), dim3(256), 0, stream>>>(pneg, ppos, lab, partial, N, nstrip);
  k_write<<<dim3(1), dim3(64), 0, stream>>>(partial, out, nfb, N);
}